// Round 3
// baseline (2997.138 us; speedup 1.0000x reference)
//
#include <hip/hip_runtime.h>
#include <hip/hip_bf16.h>
#include <math.h>

#define H_   224
#define W_   224
#define HWsz 50176      // 224*224
#define Cch  128

// ---- tiles ----
// Kernel A: output tile 8x32, halo 2 -> 12x36 staged pixels
#define TAH 8
#define TAW 32
#define HAH 12
#define HAW 36
#define NHALO_A (HAH*HAW)   // 432
// Kernel B: output tile 8x32, halo 1 -> 10x34 staged pixels
#define TBH 8
#define TBW 32
#define HBH 10
#define HBW 34
#define NHALO_B (HBH*HBW)   // 340

__device__ __forceinline__ float bf2f(__hip_bfloat16 v) { return __bfloat162float(v); }
__device__ __forceinline__ __hip_bfloat16 f2bf(float v) { return __float2bfloat16(v); }
__device__ __forceinline__ float gelu_exact(float x) {
    return 0.5f * x * (1.0f + erff(x * 0.70710678118654752440f));
}
__device__ __forceinline__ float ldv(const float* p) { return *p; }
__device__ __forceinline__ float ldv(const __hip_bfloat16* p) { return bf2f(*p); }
__device__ __forceinline__ void stv(float* p, float v) { *p = v; }
__device__ __forceinline__ void stv(__hip_bfloat16* p, float v) { *p = f2bf(v); }

// =====================================================================
// Kernel A: LN1 -> {4 shifted dw3+GELU+pw32 branches} + c5 dw3 -> shuffle
// writes z (NCHW, shuffled channel order) to workspace
// =====================================================================
template <typename ZT>
__global__ __launch_bounds__(256, 1)
void kernelA(const float* __restrict__ x,
             const float* __restrict__ n1w, const float* __restrict__ n1b,
             const float* __restrict__ c5w, const float* __restrict__ c5b,
             const float* __restrict__ s1dw, const float* __restrict__ s1db,
             const float* __restrict__ s1pw, const float* __restrict__ s1pb,
             const float* __restrict__ s2dw, const float* __restrict__ s2db,
             const float* __restrict__ s2pw, const float* __restrict__ s2pb,
             const float* __restrict__ s3dw, const float* __restrict__ s3db,
             const float* __restrict__ s3pw, const float* __restrict__ s3pb,
             const float* __restrict__ s4dw, const float* __restrict__ s4db,
             const float* __restrict__ s4pw, const float* __restrict__ s4pb,
             ZT* __restrict__ zout)
{
    __shared__ __hip_bfloat16 y_s[Cch * NHALO_A];   // 110,592 B

    const int tid = threadIdx.x;
    const int b   = blockIdx.z;
    const int h0  = blockIdx.y * TAH;
    const int w0  = blockIdx.x * TAW;

    // ---------- Phase 1: LN1 over halo pixels into y_s (bf16) ----------
    // Stats AND normalization both read f32 x from global (2nd pass L1/L2 hit)
    for (int q = tid; q < NHALO_A; q += 256) {
        const int ph = q / HAW, pw = q - ph * HAW;
        const int gy = h0 - 2 + ph, gx = w0 - 2 + pw;
        const bool valid = (gy >= 0) && (gy < H_) && (gx >= 0) && (gx < W_);
        if (valid) {
            const float* xp = x + ((size_t)b * Cch) * HWsz + (size_t)gy * W_ + gx;
            float s = 0.f, ss = 0.f;
            for (int c = 0; c < Cch; ++c) {
                float v = xp[(size_t)c * HWsz];
                s += v; ss += v * v;
            }
            const float mu  = s * (1.0f / 128.0f);
            const float var = ss * (1.0f / 128.0f) - mu * mu;
            const float rs  = rsqrtf(var + 1e-6f);
            for (int c = 0; c < Cch; ++c) {
                float v = xp[(size_t)c * HWsz];
                y_s[c * NHALO_A + q] = f2bf((v - mu) * rs * n1w[c] + n1b[c]);
            }
        } else {
            for (int c = 0; c < Cch; ++c) y_s[c * NHALO_A + q] = f2bf(0.f);
        }
    }
    __syncthreads();

    // ---------- Phase 2: branches + c5 + shuffle + write ----------
    const int py = tid >> 5;       // 0..7
    const int px = tid & 31;       // 0..31
    const int gh = h0 + py;        // global output row
    const int gw = w0 + px;        // global output col

    // dw3-on-xs SAME-pad masks: tap (t3,t4) valid iff xs-index in image.
    // xs-row = gh-1+t3, xs-col = gw-1+t4  (independent of shift sign)
    bool rowOK[3], colOK[3];
    #pragma unroll
    for (int t = 0; t < 3; ++t) {
        rowOK[t] = (gh - 1 + t >= 0) && (gh - 1 + t < H_);
        colOK[t] = (gw - 1 + t >= 0) && (gw - 1 + t < W_);
    }

    // chunk k: chunk0 (y ch 0..31) s1 sh=( 1, 1) -> out 64..95
    //          chunk1 (y 32..63)   s2 sh=(-1, 1) -> out  0..31
    //          chunk2 (y 64..95)   s3 sh=(-1,-1) -> out 96..127
    //          chunk3 (y 96..127)  s4 sh=( 1,-1) -> out 32..63
    #pragma unroll
    for (int k = 0; k < 4; ++k) {
        const float* dwW = (k == 0) ? s1dw : (k == 1) ? s2dw : (k == 2) ? s3dw : s4dw;
        const float* dwB = (k == 0) ? s1db : (k == 1) ? s2db : (k == 2) ? s3db : s4db;
        const float* pwW = (k == 0) ? s1pw : (k == 1) ? s2pw : (k == 2) ? s3pw : s4pw;
        const float* pwB = (k == 0) ? s1pb : (k == 1) ? s2pb : (k == 2) ? s3pb : s4pb;
        const int shh   = (k == 0) ? 1 : (k == 1) ? -1 : (k == 2) ? -1 : 1;
        const int shw   = (k == 0) ? 1 : (k == 1) ?  1 : (k == 2) ? -1 : -1;
        const int obase = (k == 0) ? 64 : (k == 1) ? 0 : (k == 2) ? 96 : 32;

        // shifted window: x-index of tap = y[gh-1+t3-shh, gw-1+t4-shw]
        const int rb = py + 1 - shh;   // + t3 (halo coords, origin h0-2)
        const int cb = px + 1 - shw;   // + t4

        float G[32];
        #pragma unroll
        for (int i = 0; i < 32; ++i) {
            const __hip_bfloat16* yc = y_s + (32 * k + i) * NHALO_A;
            float a = dwB[i];
            #pragma unroll
            for (int t3 = 0; t3 < 3; ++t3)
                #pragma unroll
                for (int t4 = 0; t4 < 3; ++t4) {
                    float v = (rowOK[t3] && colOK[t4])
                            ? bf2f(yc[(rb + t3) * HAW + (cb + t4)]) : 0.f;
                    a += dwW[i * 9 + t3 * 3 + t4] * v;
                }
            G[i] = gelu_exact(a);
        }

        for (int o = 0; o < 32; ++o) {
            const int c = obase + o;            // channel in pre-shuffle z
            float a = pwB[o];
            #pragma unroll
            for (int i = 0; i < 32; ++i)
                a += pwW[o * 32 + i] * G[i];
            // c5 depthwise on full-y channel c (center = halo (py+2, px+2));
            // single pad condition, zero-filled halo already correct
            const __hip_bfloat16* yc = y_s + c * NHALO_A;
            float a2 = c5b[c];
            #pragma unroll
            for (int t3 = 0; t3 < 3; ++t3)
                #pragma unroll
                for (int t4 = 0; t4 < 3; ++t4)
                    a2 += c5w[c * 9 + t3 * 3 + t4] * bf2f(yc[(py + 1 + t3) * HAW + (px + 1 + t4)]);
            // channel shuffle (2 groups): c' = 2*(c%64) + c/64
            const int cp = 2 * (c & 63) + (c >> 6);
            stv(&zout[((size_t)(b * Cch + cp)) * HWsz + (size_t)gh * W_ + gw],
                a + a2);
        }
    }
}

// =====================================================================
// Kernel B: LN2 -> dw3 -> GELU -> 128x128 pointwise -> f32 out
// =====================================================================
template <typename ZT>
__global__ __launch_bounds__(256, 1)
void kernelB(const ZT* __restrict__ z,
             const float* __restrict__ n2w, const float* __restrict__ n2b,
             const float* __restrict__ dwW, const float* __restrict__ dwB,
             const float* __restrict__ pwW, const float* __restrict__ pwB,
             float* __restrict__ out)
{
    __shared__ __hip_bfloat16 w_s[Cch * NHALO_B];   // 87,040 B

    const int tid = threadIdx.x;
    const int b   = blockIdx.z;
    const int h0  = blockIdx.y * TBH;
    const int w0  = blockIdx.x * TBW;

    // ---------- Phase 1: LN2 over halo into w_s (two-pass from global) ----------
    for (int q = tid; q < NHALO_B; q += 256) {
        const int ph = q / HBW, pw = q - ph * HBW;
        const int gy = h0 - 1 + ph, gx = w0 - 1 + pw;
        const bool valid = (gy >= 0) && (gy < H_) && (gx >= 0) && (gx < W_);
        if (valid) {
            const ZT* zp = z + ((size_t)b * Cch) * HWsz + (size_t)gy * W_ + gx;
            float s = 0.f, ss = 0.f;
            for (int c = 0; c < Cch; ++c) {
                float v = ldv(&zp[(size_t)c * HWsz]);
                s += v; ss += v * v;
            }
            const float mu  = s * (1.0f / 128.0f);
            const float var = ss * (1.0f / 128.0f) - mu * mu;
            const float rs  = rsqrtf(var + 1e-6f);
            for (int c = 0; c < Cch; ++c) {
                float v = ldv(&zp[(size_t)c * HWsz]);
                w_s[c * NHALO_B + q] = f2bf((v - mu) * rs * n2w[c] + n2b[c]);
            }
        } else {
            for (int c = 0; c < Cch; ++c) w_s[c * NHALO_B + q] = f2bf(0.f);
        }
    }
    __syncthreads();

    const int py = tid >> 5;   // 0..7
    const int px = tid & 31;   // 0..31

    // ---------- Phase 2: dw3 + GELU into per-thread register array ----------
    float g[Cch];
    #pragma unroll
    for (int c = 0; c < Cch; ++c) {
        const __hip_bfloat16* wc = w_s + c * NHALO_B;
        float a = dwB[c];
        #pragma unroll
        for (int t3 = 0; t3 < 3; ++t3)
            #pragma unroll
            for (int t4 = 0; t4 < 3; ++t4)
                a += dwW[c * 9 + t3 * 3 + t4] * bf2f(wc[(py + t3) * HBW + (px + t4)]);
        g[c] = gelu_exact(a);
    }

    // ---------- Phase 3: 128x128 pointwise (wave-uniform scalar weights) ----------
    float* op = out + ((size_t)b * Cch) * HWsz + (size_t)(h0 + py) * W_ + (w0 + px);
    for (int o = 0; o < Cch; ++o) {
        float a = pwB[o];
        #pragma unroll
        for (int c = 0; c < Cch; ++c)
            a += pwW[o * 128 + c] * g[c];
        op[(size_t)o * HWsz] = a;
    }
}

// =====================================================================
extern "C" void kernel_launch(void* const* d_in, const int* in_sizes, int n_in,
                              void* d_out, int out_size, void* d_ws, size_t ws_size,
                              hipStream_t stream)
{
    const float* x    = (const float*)d_in[0];
    const float* n1w  = (const float*)d_in[1];
    const float* n1b  = (const float*)d_in[2];
    const float* n2w  = (const float*)d_in[3];
    const float* n2b  = (const float*)d_in[4];
    const float* c5w  = (const float*)d_in[5];
    const float* c5b  = (const float*)d_in[6];
    const float* ldww = (const float*)d_in[7];
    const float* ldwb = (const float*)d_in[8];
    const float* lpww = (const float*)d_in[9];
    const float* lpwb = (const float*)d_in[10];
    const float* s1dw = (const float*)d_in[11];
    const float* s1db = (const float*)d_in[12];
    const float* s1pw = (const float*)d_in[13];
    const float* s1pb = (const float*)d_in[14];
    const float* s2dw = (const float*)d_in[15];
    const float* s2db = (const float*)d_in[16];
    const float* s2pw = (const float*)d_in[17];
    const float* s2pb = (const float*)d_in[18];
    const float* s3dw = (const float*)d_in[19];
    const float* s3db = (const float*)d_in[20];
    const float* s3pw = (const float*)d_in[21];
    const float* s3pb = (const float*)d_in[22];
    const float* s4dw = (const float*)d_in[23];
    const float* s4db = (const float*)d_in[24];
    const float* s4pw = (const float*)d_in[25];
    const float* s4pb = (const float*)d_in[26];

    dim3 grid(W_ / TAW, H_ / TAH, 8);   // (7, 28, 8)
    dim3 blk(256);

    const size_t zElems = (size_t)8 * Cch * HWsz;

    if (ws_size >= zElems * sizeof(float)) {
        float* z = (float*)d_ws;    // 205.5 MB
        kernelA<float><<<grid, blk, 0, stream>>>(x, n1w, n1b, c5w, c5b,
                                          s1dw, s1db, s1pw, s1pb,
                                          s2dw, s2db, s2pw, s2pb,
                                          s3dw, s3db, s3pw, s3pb,
                                          s4dw, s4db, s4pw, s4pb, z);
        kernelB<float><<<grid, blk, 0, stream>>>(z, n2w, n2b, ldww, ldwb, lpww, lpwb,
                                          (float*)d_out);
    } else {
        __hip_bfloat16* z = (__hip_bfloat16*)d_ws;   // 102.7 MB
        kernelA<__hip_bfloat16><<<grid, blk, 0, stream>>>(x, n1w, n1b, c5w, c5b,
                                          s1dw, s1db, s1pw, s1pb,
                                          s2dw, s2db, s2pw, s2pb,
                                          s3dw, s3db, s3pw, s3pb,
                                          s4dw, s4db, s4pw, s4pb, z);
        kernelB<__hip_bfloat16><<<grid, blk, 0, stream>>>(z, n2w, n2b, ldww, ldwb, lpww, lpwb,
                                          (float*)d_out);
    }
}

// Round 4
// 1725.812 us; speedup vs baseline: 1.7367x; 1.7367x over previous
//
#include <hip/hip_runtime.h>
#include <hip/hip_bf16.h>
#include <math.h>

#define H_   224
#define W_   224
#define HWsz 50176      // 224*224
#define Cch  128

// Kernel A: out tile 8x16, halo 2 -> 12x20
#define TAH 8
#define TAW 16
#define HAH 12
#define HAW 20
#define NHALO_A (HAH*HAW)   // 240
// Kernel B: out tile 7x32, halo 1 -> 9x34
#define TBH 7
#define TBW 32
#define HBH 9
#define HBW 34
#define NHALO_B (HBH*HBW)   // 306

__device__ __forceinline__ float bf2f(__hip_bfloat16 v) { return __bfloat162float(v); }
__device__ __forceinline__ __hip_bfloat16 f2bf(float v) { return __float2bfloat16(v); }
__device__ __forceinline__ float gelu_exact(float x) {
    return 0.5f * x * (1.0f + erff(x * 0.70710678118654752440f));
}

// =====================================================================
// ln_stats: per-pixel LN1 statistics (mu, 1/sigma) from f32 x, coalesced
// =====================================================================
__global__ __launch_bounds__(256)
void ln_stats(const float* __restrict__ x, float2* __restrict__ st)
{
    const int sp = blockIdx.x * 256 + threadIdx.x;   // 0..50175
    const int b  = blockIdx.y;
    const float* xp = x + (size_t)b * Cch * HWsz + sp;
    float s = 0.f, ss = 0.f;
    #pragma unroll 8
    for (int c = 0; c < Cch; ++c) {
        float v = xp[(size_t)c * HWsz];
        s += v; ss += v * v;
    }
    const float mu  = s * (1.0f / 128.0f);
    const float var = ss * (1.0f / 128.0f) - mu * mu;
    st[(size_t)b * HWsz + sp] = make_float2(mu, rsqrtf(var + 1e-6f));
}

// =====================================================================
// Kernel A: LN1(stats precomputed) -> 4 shift branches + c5 -> shuffle
// -> z (bf16) + LN2 stats (computed in-thread over all 128 channels)
// =====================================================================
__global__ __launch_bounds__(256, 2)
void kernelA(const float* __restrict__ x, const float2* __restrict__ st1,
             const float* __restrict__ n1w, const float* __restrict__ n1b,
             const float* __restrict__ c5w, const float* __restrict__ c5b,
             const float* __restrict__ s1dw, const float* __restrict__ s1db,
             const float* __restrict__ s1pw, const float* __restrict__ s1pb,
             const float* __restrict__ s2dw, const float* __restrict__ s2db,
             const float* __restrict__ s2pw, const float* __restrict__ s2pb,
             const float* __restrict__ s3dw, const float* __restrict__ s3db,
             const float* __restrict__ s3pw, const float* __restrict__ s3pb,
             const float* __restrict__ s4dw, const float* __restrict__ s4db,
             const float* __restrict__ s4pw, const float* __restrict__ s4pb,
             __hip_bfloat16* __restrict__ zout, float2* __restrict__ st2)
{
    __shared__ __hip_bfloat16 y_s[Cch * NHALO_A];   // 61,440 B
    __shared__ float red_s[TAH * TAW], red_ss[TAH * TAW];   // 1 KB

    const int tid = threadIdx.x;
    const int b   = blockIdx.z;
    const int h0  = blockIdx.y * TAH;
    const int w0  = blockIdx.x * TAW;

    // ---------- Phase 1: single-pass LN1 into y_s ----------
    if (tid < NHALO_A) {
        const int ph = tid / HAW, pw = tid - ph * HAW;
        const int gy = h0 - 2 + ph, gx = w0 - 2 + pw;
        if (gy >= 0 && gy < H_ && gx >= 0 && gx < W_) {
            const float2 st = st1[(size_t)b * HWsz + gy * W_ + gx];
            const float* xp = x + (size_t)b * Cch * HWsz + (size_t)gy * W_ + gx;
            #pragma unroll 8
            for (int c = 0; c < Cch; ++c) {
                float v = xp[(size_t)c * HWsz];
                y_s[c * NHALO_A + tid] = f2bf((v - st.x) * st.y * n1w[c] + n1b[c]);
            }
        } else {
            for (int c = 0; c < Cch; ++c) y_s[c * NHALO_A + tid] = f2bf(0.f);
        }
    }
    __syncthreads();

    // ---------- Phase 2: (pixel x chunk-half) split, wave-uniform half ----------
    const int lane = tid & 63;
    const int wv   = tid >> 6;
    const int half = wv >> 1;                 // wave-uniform: waves 0,1 -> 0; 2,3 -> 1
    const int p    = ((wv & 1) << 6) | lane;  // 0..127
    const int py   = p >> 4, px = p & 15;
    const int gh   = h0 + py, gw = w0 + px;

    // dw3-on-xs SAME-pad masks (shift-independent)
    bool rowOK[3], colOK[3];
    #pragma unroll
    for (int t = 0; t < 3; ++t) {
        rowOK[t] = (gh - 1 + t >= 0) && (gh - 1 + t < H_);
        colOK[t] = (gw - 1 + t >= 0) && (gw - 1 + t < W_);
    }

    float s = 0.f, ss = 0.f;

    #pragma unroll
    for (int kk = 0; kk < 2; ++kk) {
        const int k = half * 2 + kk;   // wave-uniform chunk id
        const float* dwW = (k == 0) ? s1dw : (k == 1) ? s2dw : (k == 2) ? s3dw : s4dw;
        const float* dwB = (k == 0) ? s1db : (k == 1) ? s2db : (k == 2) ? s3db : s4db;
        const float* pwW = (k == 0) ? s1pw : (k == 1) ? s2pw : (k == 2) ? s3pw : s4pw;
        const float* pwB = (k == 0) ? s1pb : (k == 1) ? s2pb : (k == 2) ? s3pb : s4pb;
        const int shh   = (k == 0) ? 1 : (k == 1) ? -1 : (k == 2) ? -1 : 1;
        const int shw   = (k == 0) ? 1 : (k == 1) ?  1 : (k == 2) ? -1 : -1;
        const int obase = (k == 0) ? 64 : (k == 1) ? 0 : (k == 2) ? 96 : 32;

        const int rb = py + 1 - shh;
        const int cb = px + 1 - shw;

        float G[32];
        #pragma unroll
        for (int i = 0; i < 32; ++i) {
            const __hip_bfloat16* yc = y_s + (32 * k + i) * NHALO_A;
            float a = dwB[i];
            #pragma unroll
            for (int t3 = 0; t3 < 3; ++t3)
                #pragma unroll
                for (int t4 = 0; t4 < 3; ++t4) {
                    float v = (rowOK[t3] && colOK[t4])
                            ? bf2f(yc[(rb + t3) * HAW + (cb + t4)]) : 0.f;
                    a += dwW[i * 9 + t3 * 3 + t4] * v;
                }
            G[i] = gelu_exact(a);
        }

        for (int o = 0; o < 32; ++o) {
            const int c = obase + o;
            float a = pwB[o];
            #pragma unroll
            for (int i = 0; i < 32; ++i)
                a += pwW[o * 32 + i] * G[i];
            const __hip_bfloat16* yc = y_s + c * NHALO_A;
            float a2 = c5b[c];
            #pragma unroll
            for (int t3 = 0; t3 < 3; ++t3)
                #pragma unroll
                for (int t4 = 0; t4 < 3; ++t4)
                    a2 += c5w[c * 9 + t3 * 3 + t4] * bf2f(yc[(py + 1 + t3) * HAW + (px + 1 + t4)]);
            const __hip_bfloat16 zv = f2bf(a + a2);
            const float vf = bf2f(zv);      // stats on the rounded value (what B reads)
            s += vf; ss += vf * vf;
            const int cp = 2 * (c & 63) + (c >> 6);   // channel shuffle
            zout[((size_t)(b * Cch + cp)) * HWsz + (size_t)gh * W_ + gw] = zv;
        }
    }

    // ---------- LN2 stats: combine the two halves via LDS ----------
    if (half == 0) { red_s[p] = s; red_ss[p] = ss; }
    __syncthreads();
    if (half == 1) {
        const float S  = red_s[p] + s;
        const float SS = red_ss[p] + ss;
        const float mu  = S * (1.0f / 128.0f);
        const float var = SS * (1.0f / 128.0f) - mu * mu;
        st2[(size_t)b * HWsz + gh * W_ + gw] = make_float2(mu, rsqrtf(var + 1e-6f));
    }
}

// =====================================================================
// Kernel B: LN2(stats precomputed) -> dw3 -> GELU -> 128x128 pw -> f32
// =====================================================================
__global__ __launch_bounds__(256, 2)
void kernelB(const __hip_bfloat16* __restrict__ z, const float2* __restrict__ st2,
             const float* __restrict__ n2w, const float* __restrict__ n2b,
             const float* __restrict__ dwW, const float* __restrict__ dwB,
             const float* __restrict__ pwW, const float* __restrict__ pwB,
             float* __restrict__ out)
{
    __shared__ __hip_bfloat16 w_s[Cch * NHALO_B];   // 78,336 B

    const int tid = threadIdx.x;
    const int b   = blockIdx.z;
    const int h0  = blockIdx.y * TBH;
    const int w0  = blockIdx.x * TBW;

    // ---------- Phase 1: single-pass LN2 into w_s ----------
    for (int q = tid; q < NHALO_B; q += 256) {
        const int ph = q / HBW, pw = q - ph * HBW;
        const int gy = h0 - 1 + ph, gx = w0 - 1 + pw;
        if (gy >= 0 && gy < H_ && gx >= 0 && gx < W_) {
            const float2 st = st2[(size_t)b * HWsz + gy * W_ + gx];
            const __hip_bfloat16* zp = z + (size_t)b * Cch * HWsz + (size_t)gy * W_ + gx;
            #pragma unroll 8
            for (int c = 0; c < Cch; ++c) {
                float v = bf2f(zp[(size_t)c * HWsz]);
                w_s[c * NHALO_B + q] = f2bf((v - st.x) * st.y * n2w[c] + n2b[c]);
            }
        } else {
            for (int c = 0; c < Cch; ++c) w_s[c * NHALO_B + q] = f2bf(0.f);
        }
    }
    __syncthreads();

    if (tid >= TBH * TBW) return;   // 224 active
    const int py = tid >> 5;   // 0..6
    const int px = tid & 31;   // 0..31

    // ---------- Phase 2: dw3 + GELU ----------
    float g[Cch];
    #pragma unroll
    for (int c = 0; c < Cch; ++c) {
        const __hip_bfloat16* wc = w_s + c * NHALO_B;
        float a = dwB[c];
        #pragma unroll
        for (int t3 = 0; t3 < 3; ++t3)
            #pragma unroll
            for (int t4 = 0; t4 < 3; ++t4)
                a += dwW[c * 9 + t3 * 3 + t4] * bf2f(wc[(py + t3) * HBW + (px + t4)]);
        g[c] = gelu_exact(a);
    }

    // ---------- Phase 3: 128x128 pointwise ----------
    float* op = out + (size_t)b * Cch * HWsz + (size_t)(h0 + py) * W_ + (w0 + px);
    for (int o = 0; o < Cch; ++o) {
        float a = pwB[o];
        #pragma unroll
        for (int c = 0; c < Cch; ++c)
            a += pwW[o * 128 + c] * g[c];
        op[(size_t)o * HWsz] = a;
    }
}

// =====================================================================
extern "C" void kernel_launch(void* const* d_in, const int* in_sizes, int n_in,
                              void* d_out, int out_size, void* d_ws, size_t ws_size,
                              hipStream_t stream)
{
    const float* x    = (const float*)d_in[0];
    const float* n1w  = (const float*)d_in[1];
    const float* n1b  = (const float*)d_in[2];
    const float* n2w  = (const float*)d_in[3];
    const float* n2b  = (const float*)d_in[4];
    const float* c5w  = (const float*)d_in[5];
    const float* c5b  = (const float*)d_in[6];
    const float* ldww = (const float*)d_in[7];
    const float* ldwb = (const float*)d_in[8];
    const float* lpww = (const float*)d_in[9];
    const float* lpwb = (const float*)d_in[10];
    const float* s1dw = (const float*)d_in[11];
    const float* s1db = (const float*)d_in[12];
    const float* s1pw = (const float*)d_in[13];
    const float* s1pb = (const float*)d_in[14];
    const float* s2dw = (const float*)d_in[15];
    const float* s2db = (const float*)d_in[16];
    const float* s2pw = (const float*)d_in[17];
    const float* s2pb = (const float*)d_in[18];
    const float* s3dw = (const float*)d_in[19];
    const float* s3db = (const float*)d_in[20];
    const float* s3pw = (const float*)d_in[21];
    const float* s3pb = (const float*)d_in[22];
    const float* s4dw = (const float*)d_in[23];
    const float* s4db = (const float*)d_in[24];
    const float* s4pw = (const float*)d_in[25];
    const float* s4pb = (const float*)d_in[26];

    // workspace layout: z (bf16) | st1 (float2) | st2 (float2)
    const size_t zBytes  = (size_t)8 * Cch * HWsz * sizeof(__hip_bfloat16); // 102,760,448
    const size_t stBytes = (size_t)8 * HWsz * sizeof(float2);               //   3,211,264
    __hip_bfloat16* z = (__hip_bfloat16*)d_ws;
    float2* st1 = (float2*)((char*)d_ws + zBytes);
    float2* st2 = (float2*)((char*)d_ws + zBytes + stBytes);

    ln_stats<<<dim3(HWsz / 256, 8), 256, 0, stream>>>(x, st1);

    kernelA<<<dim3(W_ / TAW, H_ / TAH, 8), 256, 0, stream>>>(
        x, st1, n1w, n1b, c5w, c5b,
        s1dw, s1db, s1pw, s1pb,
        s2dw, s2db, s2pw, s2pb,
        s3dw, s3db, s3pw, s3pb,
        s4dw, s4db, s4pw, s4pb, z, st2);

    kernelB<<<dim3(W_ / TBW, H_ / TBH, 8), 256, 0, stream>>>(
        z, st2, n2w, n2b, ldww, ldwb, lpww, lpwb, (float*)d_out);
}